// Round 16
// baseline (330.744 us; speedup 1.0000x reference)
//
#include <hip/hip_runtime.h>

typedef unsigned short u16;
typedef unsigned int u32;
typedef __attribute__((ext_vector_type(8))) short bf8;
typedef __attribute__((ext_vector_type(4))) float f4;
typedef __attribute__((ext_vector_type(4))) unsigned short us4;

constexpr int B = 2;
constexpr int NQ = 1024;
constexpr int C = 2048;
constexpr int DH = 128;
constexpr int G = 4;
constexpr int CD = 512;
constexpr int LR = 24;
constexpr int HR = 72;
constexpr int INTER = 64;
constexpr int K = LR * LR;  // 576
constexpr int NKV = NQ + K; // 1600

#define MFMA16(a, b, c) __builtin_amdgcn_mfma_f32_16x16x32_bf16(a, b, c, 0, 0, 0)
#define GLDS(g, l)                                                         \
  __builtin_amdgcn_global_load_lds(                                        \
      (const __attribute__((address_space(1))) void*)(g),                  \
      (__attribute__((address_space(3))) void*)(l), 16, 0, 0)
#define SB()                               \
  do {                                     \
    __builtin_amdgcn_sched_barrier(0);     \
    __builtin_amdgcn_s_barrier();          \
    __builtin_amdgcn_sched_barrier(0);     \
  } while (0)
#define WVM(n)                                              \
  do {                                                      \
    asm volatile("s_waitcnt vmcnt(" #n ")" ::: "memory");   \
    __builtin_amdgcn_sched_barrier(0);                      \
  } while (0)

__device__ __forceinline__ u16 f2bf1(float f) {
  u32 u = __float_as_uint(f);
  u32 r = (u + 0x7fffu + ((u >> 16) & 1u)) >> 16;
  return (u16)r;
}

// ---- L1: fp32->bf16 STAGED (7) + plrw^T + dwconv/pool, one launch ----------
__global__ __launch_bounds__(256) void f2bf_k9b(
    const float* __restrict__ s0, const float* __restrict__ s1,
    const float* __restrict__ s2, const float* __restrict__ s3,
    const float* __restrict__ s4, const float* __restrict__ s5,
    const float* __restrict__ s6, const float* __restrict__ plrw,
    const float* __restrict__ cdw, u16* __restrict__ d0, u16* __restrict__ d1,
    u16* __restrict__ d2, u16* __restrict__ d3, u16* __restrict__ d4,
    u16* __restrict__ d5, u16* __restrict__ d6, float* __restrict__ wt,
    float* __restrict__ x1, float* __restrict__ pooled) {
  __shared__ float SH[16 * 577];
  const int y = blockIdx.y;
  const int t = threadIdx.x;
  if (y == 7) {
    if (blockIdx.x >= 128) return;
    const int idx = blockIdx.x * 256 + t;
    wt[idx] = plrw[(idx & 63) * 512 + (idx >> 6)];
    return;
  }
  if (y == 8) {
    if (blockIdx.x >= 256) return;
    const int n = blockIdx.x >> 5, cg = blockIdx.x & 31;
    const int b = n >> 2, g = n & 3;
    const int c0 = cg * 16;
    {
      const int c = t & 15, pr = t >> 4;
      const float* src = s0 + (size_t)b * 1024 * 2048 + g * 512 + c0 + c;
#pragma unroll 4
      for (int j = 0; j < 36; ++j) {
        const int p = j * 16 + pr;
        SH[c * 577 + p] = src[(size_t)p * 2048];
      }
    }
    __syncthreads();
    {
      const int c = t >> 4, seg = t & 15;
      float s = 0.f;
      for (int i = 0; i < 36; ++i) s += SH[c * 577 + seg * 36 + i];
      s += __shfl_xor(s, 1);
      s += __shfl_xor(s, 2);
      s += __shfl_xor(s, 4);
      s += __shfl_xor(s, 8);
      if (seg == 0) pooled[n * 512 + c0 + c] = s * (1.f / 576.f);
    }
    const size_t base_out = (size_t)(n * 512 + c0) * 576;
    for (int j = 0; j < 36; ++j) {
      const int idx = j * 256 + t;
      const int c = idx / 576, p = idx - c * 576;
      const int yy0 = p / 24, xx0 = p - yy0 * 24;
      const float* wp = cdw + (c0 + c) * 9;
      float s = 0.f;
#pragma unroll
      for (int dy = -1; dy <= 1; ++dy)
#pragma unroll
        for (int dx = -1; dx <= 1; ++dx) {
          const int yy = yy0 + dy, xx = xx0 + dx;
          if (yy < 0 || yy >= 24 || xx < 0 || xx >= 24) continue;
          s += SH[c * 577 + yy * 24 + xx] * wp[(dy + 1) * 3 + dx + 1];
        }
      x1[base_out + idx] = s / (1.f + expf(-s));
    }
    return;
  }
  const float* s;
  u16* d;
  switch (y) {
    case 0: s = s0; d = d0; break;
    case 1: s = s1; d = d1; break;
    case 2: s = s2; d = d2; break;
    case 3: s = s3; d = d3; break;
    case 4: s = s4; d = d4; break;
    case 5: s = s5; d = d5; break;
    default: s = s6; d = d6; break;
  }
  u16* L = (u16*)SH;  // [64][68]
  const int pc = blockIdx.x;
  const int mb = pc >> 5, kb = pc & 31;
  const int rin = t >> 2, c0 = (t & 3) * 16;
  const float* src = s + (size_t)(mb * 64 + rin) * 2048 + kb * 64 + c0;
#pragma unroll
  for (int j = 0; j < 16; j += 4) {
    float4 v = *(const float4*)(src + j);
    L[rin * 68 + c0 + j] = f2bf1(v.x);
    L[rin * 68 + c0 + j + 1] = f2bf1(v.y);
    L[rin * 68 + c0 + j + 2] = f2bf1(v.z);
    L[rin * 68 + c0 + j + 3] = f2bf1(v.w);
  }
  __syncthreads();
  u16* dst = d + (size_t)pc * 4096 + t * 16;
#pragma unroll
  for (int gg = 0; gg < 2; ++gg) {
    const int g = t * 2 + gg;
    const int rh = g & 15, ks2 = (g >> 4) & 3, kc = (g >> 6) & 1, fr = g >> 7;
    const int row = fr * 16 + rh, cc = kc * 32 + ks2 * 8;
    us4 o0, o1;
    o0.x = L[row * 68 + cc];     o0.y = L[row * 68 + cc + 1];
    o0.z = L[row * 68 + cc + 2]; o0.w = L[row * 68 + cc + 3];
    o1.x = L[row * 68 + cc + 4]; o1.y = L[row * 68 + cc + 5];
    o1.z = L[row * 68 + cc + 6]; o1.w = L[row * 68 + cc + 7];
    *(us4*)(dst + gg * 8) = o0;
    *(us4*)(dst + gg * 8 + 4) = o1;
  }
}

// ------------------ QKV 256x256 8-phase MFMA GEMM (192 blocks) --------------
__global__ __launch_bounds__(512, 2) void gemm256(
    const u16* __restrict__ Ast, const u16* __restrict__ Wq,
    const u16* __restrict__ Wk, const u16* __restrict__ Wv,
    u16* __restrict__ outq, u16* __restrict__ kg, u16* __restrict__ vg) {
  __shared__ u16 As[2][4][4096];
  __shared__ u16 Bs[2][4][4096];
  const int tid = threadIdx.x, lane = tid & 63, w = tid >> 6;
  const int ks = lane >> 4, r = lane & 15;
  const int bid = blockIdx.x;
  const int wm = w >> 2, wn = w & 3;
  const int swz = (bid & 7) * 24 + (bid >> 3);
  const int mt = swz / 24, nt = swz % 24;
  const u16* Wst = (nt < 8) ? Wq : (nt < 16) ? Wk : Wv;
  const int nb0 = (nt & 7) * 4;
  const int mb0 = mt * 4;

#define ST_A03(bi, kt)                                                        \
  do {                                                                        \
    GLDS(Ast + ((size_t)(mb0 + 0) * 32 + (kt)) * 4096 + tid * 8,              \
         &As[bi][0][tid * 8]);                                                \
    GLDS(Ast + ((size_t)(mb0 + 2) * 32 + (kt)) * 4096 + tid * 8,              \
         &As[bi][2][tid * 8]);                                                \
  } while (0)
#define ST_A47(bi, kt)                                                        \
  do {                                                                        \
    GLDS(Ast + ((size_t)(mb0 + 1) * 32 + (kt)) * 4096 + tid * 8,              \
         &As[bi][1][tid * 8]);                                                \
    GLDS(Ast + ((size_t)(mb0 + 3) * 32 + (kt)) * 4096 + tid * 8,              \
         &As[bi][3][tid * 8]);                                                \
  } while (0)
#define ST_B01(bi, kt)                                                        \
  do {                                                                        \
    GLDS(Wst + ((size_t)(nb0 + 0) * 32 + (kt)) * 4096 + tid * 8,              \
         &Bs[bi][0][tid * 8]);                                                \
    GLDS(Wst + ((size_t)(nb0 + 1) * 32 + (kt)) * 4096 + tid * 8,              \
         &Bs[bi][1][tid * 8]);                                                \
  } while (0)
#define ST_B23(bi, kt)                                                        \
  do {                                                                        \
    GLDS(Wst + ((size_t)(nb0 + 2) * 32 + (kt)) * 4096 + tid * 8,              \
         &Bs[bi][2][tid * 8]);                                                \
    GLDS(Wst + ((size_t)(nb0 + 3) * 32 + (kt)) * 4096 + tid * 8,              \
         &Bs[bi][3][tid * 8]);                                                \
  } while (0)
#define RD_A(dst, bi, half, kc)                                               \
  _Pragma("unroll") for (int i2 = 0; i2 < 4; ++i2) dst[i2] =                  \
      *(const bf8*)(&As[bi][wm * 2 + (half)]                                  \
                       [((i2 * 2 + (kc)) * 4 + ks) * 128 + r * 8]);
#define RD_B(dst, bi, kc)                                                     \
  _Pragma("unroll") for (int j2 = 0; j2 < 4; ++j2) dst[j2] =                  \
      *(const bf8*)(&Bs[bi][wn][((j2 * 2 + (kc)) * 4 + ks) * 128 + r * 8]);
#define MM(ACC, AF, BF)                                                       \
  do {                                                                        \
    __builtin_amdgcn_s_setprio(1);                                            \
    _Pragma("unroll") for (int i3 = 0; i3 < 4; ++i3)                          \
        _Pragma("unroll") for (int j3 = 0; j3 < 4; ++j3) ACC[i3][j3] =        \
            MFMA16(AF[i3], BF[j3], ACC[i3][j3]);                              \
    __builtin_amdgcn_s_setprio(0);                                            \
  } while (0)

  f4 accA[4][4], accB[4][4];
#pragma unroll
  for (int i = 0; i < 4; ++i)
#pragma unroll
    for (int j = 0; j < 4; ++j) {
      accA[i][j] = f4{0.f, 0.f, 0.f, 0.f};
      accB[i][j] = f4{0.f, 0.f, 0.f, 0.f};
    }
  bf8 af[4], b0[4], b1[4];

  ST_A03(0, 0); ST_B01(0, 0); ST_B23(0, 0); ST_A47(0, 0);
  ST_A03(1, 1); ST_B01(1, 1);
  WVM(6);
  SB();

  for (int t = 0; t < 32; ++t) {
    const int buf = t & 1;
    RD_A(af, buf, 0, 0);
    RD_B(b0, buf, 0);
    if (t + 1 < 32) ST_B23(buf ^ 1, t + 1);
    SB();
    MM(accA, af, b0);
    SB();
    RD_A(af, buf, 0, 1);
    RD_B(b1, buf, 1);
    if (t + 1 < 32) ST_A47(buf ^ 1, t + 1);
    SB();
    MM(accA, af, b1);
    if (t + 1 < 32) { WVM(8); } else { WVM(0); }
    SB();
    RD_A(af, buf, 1, 0);
    if (t + 2 < 32) ST_A03(buf, t + 2);
    SB();
    MM(accB, af, b0);
    SB();
    RD_A(af, buf, 1, 1);
    if (t + 2 < 32) ST_B01(buf, t + 2);
    SB();
    MM(accB, af, b1);
    if (t + 2 < 32) { WVM(6); } else if (t + 1 < 32) { WVM(2); }
    SB();
  }

#define EPI(ACC, HALF)                                                        \
  _Pragma("unroll") for (int i = 0; i < 4; ++i)                               \
      _Pragma("unroll") for (int j = 0; j < 4; ++j)                           \
          _Pragma("unroll") for (int rr = 0; rr < 4; ++rr) {                  \
    const int m = mt * 256 + wm * 128 + (HALF)*64 + i * 16 + ks * 4 + rr;     \
    const int n = nt * 256 + wn * 64 + j * 16 + r;                            \
    const float v = ACC[i][j][rr];                                            \
    const int sel = n >> 11, nn = n & 2047, hh = nn >> 7, dd = nn & 127;      \
    const int bb = m >> 10, qq = m & 1023;                                    \
    const u16 bv = f2bf1(v);                                                  \
    if (sel == 0) {                                                           \
      outq[(size_t)m * 2048 + nn] = bv;                                       \
    } else if (sel == 1) {                                                    \
      kg[(((size_t)(bb * 16 + hh) * 50 + (qq >> 5)) * 16 + (dd >> 3)) * 256 + \
         (qq & 31) * 8 + (dd & 7)] = bv;                                      \
    } else {                                                                  \
      vg[((size_t)(bb * 16 + hh) * 200 + (qq >> 3)) * 1024 + dd * 8 +         \
         (qq & 7)] = bv;                                                      \
    }                                                                         \
  }
  EPI(accA, 0)
  EPI(accB, 1)
#undef EPI
}

// ---- HD k/v single 128^2 tiles (288 blocks, 48KB LDS -> 3 blocks/CU) -------
__global__ __launch_bounds__(512) void gemm_hd1(
    const u16* __restrict__ sampst, const u16* __restrict__ khwst,
    const u16* __restrict__ vhwst, const float* __restrict__ khb,
    const float* __restrict__ vhb, u16* __restrict__ kg,
    u16* __restrict__ vg) {
  __shared__ u16 A3[3 * 4096];
  __shared__ u16 B3[3 * 4096];
  const int tid = threadIdx.x, lane = tid & 63, w = tid >> 6;
  const int ks = lane >> 4, r = lane & 15;
  const int htile = blockIdx.x;  // 0..287
  const bool is_v = (htile >= 144);
  const int hb = is_v ? (htile - 144) : htile;
  const int mt = hb / 16, nt = hb % 16;
  const int ma0 = mt * 2, nb0 = nt * 2;
  const int wr = w >> 2, wc = w & 3;
  const u16* Wsrc = is_v ? vhwst : khwst;

#define HDS1(bi, kt)                                                          \
  do {                                                                        \
    const int kb_ = (kt) >> 1, kc_ = (kt) & 1;                                \
    GLDS(sampst + ((size_t)(ma0 + (w >> 2)) * 32 + kb_) * 4096 +              \
             (w & 3) * 1024 + kc_ * 512 + lane * 8,                           \
         &A3[(bi)*4096 + w * 512 + lane * 8]);                                \
    GLDS(Wsrc + ((size_t)(nb0 + (w >> 2)) * 32 + kb_) * 4096 +                \
             (w & 3) * 1024 + kc_ * 512 + lane * 8,                           \
         &B3[(bi)*4096 + w * 512 + lane * 8]);                                \
  } while (0)

  f4 acc[4][2];
#pragma unroll
  for (int i = 0; i < 4; ++i)
#pragma unroll
    for (int j = 0; j < 2; ++j) acc[i][j] = f4{0.f, 0.f, 0.f, 0.f};

  HDS1(0, 0);
  HDS1(1, 1);
  int rd = 0;
  for (int kt = 0; kt < 64; ++kt) {
    SB();  // B1: closes iter kt-1's LDS reads
    if (kt + 2 < 64) {
      const int wb = (rd + 2 >= 3) ? rd - 1 : rd + 2;
      HDS1(wb, kt + 2);
      WVM(4);  // my 2 loads for tile kt landed (kt+1,kt+2 in flight)
    } else if (kt + 1 < 64) {
      WVM(2);
    } else {
      WVM(0);
    }
    SB();  // B2: all waves' tile-kt loads landed
    bf8 af2[4], bw[2];
#pragma unroll
    for (int i = 0; i < 4; ++i)
      af2[i] =
          *(const bf8*)(&A3[rd * 4096 + (wr * 4 + i) * 512 + ks * 128 + r * 8]);
#pragma unroll
    for (int j = 0; j < 2; ++j)
      bw[j] =
          *(const bf8*)(&B3[rd * 4096 + (wc * 2 + j) * 512 + ks * 128 + r * 8]);
    __builtin_amdgcn_s_setprio(1);
#pragma unroll
    for (int i = 0; i < 4; ++i)
#pragma unroll
      for (int j = 0; j < 2; ++j)
        acc[i][j] = MFMA16(af2[i], bw[j], acc[i][j]);
    __builtin_amdgcn_s_setprio(0);
    rd = (rd + 1 >= 3) ? 0 : rd + 1;
  }
#undef HDS1
  const int rbase = ks * 4;
  const float* bias = is_v ? vhb : khb;
#pragma unroll
  for (int i = 0; i < 4; ++i)
#pragma unroll
    for (int j = 0; j < 2; ++j) {
      const int nn = nt * 128 + (wc * 2 + j) * 16 + r;
      const int hh = nn >> 7, dd = nn & 127;
#pragma unroll
      for (int rr = 0; rr < 4; ++rr) {
        const int m = mt * 128 + wr * 64 + i * 16 + rbase + rr;
        const int bb = m / 576;
        const int kv = 1024 + (m - bb * 576);
        const u16 bv = f2bf1(acc[i][j][rr] + bias[nn]);
        if (!is_v) {
          kg[(((size_t)(bb * 16 + hh) * 50 + (kv >> 5)) * 16 + (dd >> 3)) *
                 256 +
             (kv & 31) * 8 + (dd & 7)] = bv;
        } else {
          vg[((size_t)(bb * 16 + hh) * 200 + (kv >> 3)) * 1024 + dd * 8 +
             (kv & 7)] = bv;
        }
      }
    }
}

// ---- output projection: staged x staged, 3-buffer 2-deep pipeline ----------
__global__ __launch_bounds__(256) void gemm_out3(const u16* __restrict__ Ast,
                                                 const u16* __restrict__ W0,
                                                 float* __restrict__ outf) {
  __shared__ u16 As[3][4096];
  __shared__ u16 Bs[3][4096];
  const int tid = threadIdx.x, lane = tid & 63, w = tid >> 6;
  const int wr = w >> 1, wc = w & 1;
  const int ksl = lane >> 4, rl = lane & 15;
  const int xcd = blockIdx.x & 7, idx = blockIdx.x >> 3;
  const int mt = (xcd >> 2) * 8 + idx / 4;
  const int nt = (xcd & 3) * 4 + idx % 4;
  const u16* Wp = W0;
  const int ma0 = mt * 2;
  const int nb0 = nt * 2;

#define GST2(dstArr, srcBase, tb0, kt)                                     \
  do {                                                                     \
    const int kb_ = (kt) >> 1, kc_ = (kt) & 1;                             \
    _Pragma("unroll") for (int r2 = 0; r2 < 2; ++r2) {                     \
      const int run = r2 * 4 + w;                                          \
      GLDS(srcBase + ((size_t)((tb0) + (run >> 2)) * 32 + kb_) * 4096 +    \
               (run & 3) * 1024 + kc_ * 512 + lane * 8,                    \
           &dstArr[run * 512 + lane * 8]);                                 \
    }                                                                      \
  } while (0)

  f4 acc[4][4];
#pragma unroll
  for (int i = 0; i < 4; ++i)
#pragma unroll
    for (int j = 0; j < 4; ++j) acc[i][j] = f4{0.f, 0.f, 0.f, 0.f};

  GST2(As[0], Ast, ma0, 0);
  GST2(Bs[0], Wp, nb0, 0);
  GST2(As[1], Ast, ma0, 1);
  GST2(Bs[1], Wp, nb0, 1);
  int rd = 0;
  for (int kt = 0; kt < 64; ++kt) {
    SB();
    if (kt + 2 < 64) {
      const int wb = (rd + 2 >= 3) ? rd - 1 : rd + 2;
      GST2(As[wb], Ast, ma0, kt + 2);
      GST2(Bs[wb], Wp, nb0, kt + 2);
      WVM(8);
    } else if (kt + 1 < 64) {
      WVM(4);
    } else {
      WVM(0);
    }
    SB();
    bf8 af[4], bw[4];
#pragma unroll
    for (int i = 0; i < 4; ++i)
      af[i] = *(const bf8*)(&As[rd][(wr * 4 + i) * 512 + ksl * 128 + rl * 8]);
#pragma unroll
    for (int j = 0; j < 4; ++j)
      bw[j] = *(const bf8*)(&Bs[rd][(wc * 4 + j) * 512 + ksl * 128 + rl * 8]);
    __builtin_amdgcn_s_setprio(1);
#pragma unroll
    for (int i = 0; i < 4; ++i)
#pragma unroll
      for (int j = 0; j < 4; ++j)
        acc[i][j] = MFMA16(af[i], bw[j], acc[i][j]);
    __builtin_amdgcn_s_setprio(0);
    rd = (rd + 1 >= 3) ? 0 : rd + 1;
  }
#undef GST2

  const int rbase = ksl * 4;
#pragma unroll
  for (int i = 0; i < 4; ++i)
#pragma unroll
    for (int j = 0; j < 4; ++j) {
      const int n = nt * 128 + wc * 64 + j * 16 + rl;
#pragma unroll
      for (int rr = 0; rr < 4; ++rr) {
        const int m = mt * 128 + wr * 64 + i * 16 + rbase + rr;
        outf[(size_t)m * 2048 + n] = acc[i][j][rr];
      }
    }
}

// -------------- offset network: fused LN(512)+1x1conv + gate ----------------
__global__ __launch_bounds__(256) void lnproj_gate(
    const float* __restrict__ x1, const float* __restrict__ ln1w,
    const float* __restrict__ ln1b, const float* __restrict__ wt,
    const float* __restrict__ pooled, const float* __restrict__ piw,
    const float* __restrict__ pib, float* __restrict__ x2,
    float* __restrict__ gate) {
  __shared__ float Xs[512][68];
  __shared__ float rs[4][64], rss[4][64];
  const int bidx = blockIdx.x;
  const int t = threadIdx.x;
  if (bidx >= 72) {
    const int idx = (bidx - 72) * 256 + t;
    const int n = idx >> 6, o = idx & 63;
    const float* pb = pooled + n * 512;
    const float* wb = piw + o * 512;
    float s = pib[o];
    for (int c = 0; c < 512; ++c) s += pb[c] * wb[c];
    gate[idx] = 1.f / (1.f + expf(-s));
    return;
  }
  const int n = bidx / 9, pc = bidx % 9;
  const int p0 = pc * 64;
  {
    const int pl = t & 63, c4 = t >> 6;
    const float* src = x1 + (size_t)n * 512 * 576 + p0 + pl;
#pragma unroll 4
    for (int j = 0; j < 128; ++j) {
      const int c = j * 4 + c4;
      Xs[c][pl] = src[(size_t)c * 576];
    }
  }
  __syncthreads();
  {
    const int pl = t & 63, q = t >> 6;
    float s = 0.f, ss = 0.f;
    for (int c = q * 128; c < q * 128 + 128; ++c) {
      const float v = Xs[c][pl];
      s += v;
      ss += v * v;
    }
    rs[q][pl] = s;
    rss[q][pl] = ss;
    __syncthreads();
    const float S = rs[0][pl] + rs[1][pl] + rs[2][pl] + rs[3][pl];
    const float SS = rss[0][pl] + rss[1][pl] + rss[2][pl] + rss[3][pl];
    const float mean = S * (1.f / 512.f);
    const float inv = rsqrtf(SS * (1.f / 512.f) - mean * mean + 1e-5f);
    for (int c = q * 128; c < q * 128 + 128; ++c)
      Xs[c][pl] = (Xs[c][pl] - mean) * inv * ln1w[c] + ln1b[c];
  }
  __syncthreads();
  {
    const int o4 = (t & 15) * 4, pl0 = (t >> 4) * 4;
    float acc[4][4] = {};
    for (int c = 0; c < 512; ++c) {
      const f4 xv = *(const f4*)(&Xs[c][pl0]);
      const f4 wv = *(const f4*)(&wt[c * 64 + o4]);
#pragma unroll
      for (int i = 0; i < 4; ++i)
#pragma unroll
        for (int j = 0; j < 4; ++j) acc[i][j] += wv[i] * xv[j];
    }
#pragma unroll
    for (int i = 0; i < 4; ++i) {
      f4 ov;
      ov[0] = acc[i][0]; ov[1] = acc[i][1];
      ov[2] = acc[i][2]; ov[3] = acc[i][3];
      *(f4*)(&x2[(size_t)(n * 64 + o4 + i) * 576 + p0 + pl0]) = ov;
    }
  }
}

// ------- fused: LN(64)+offsets+tanh positions + bilinear sample -> STAGED ---
__global__ __launch_bounds__(256) void pos_sample(
    const float* __restrict__ x2, const float* __restrict__ gate,
    const float* __restrict__ ln2w, const float* __restrict__ ln2b,
    const float* __restrict__ offw, const float* __restrict__ img,
    u16* __restrict__ sampst) {
  const int bk = blockIdx.x;
  const int b = bk / K, k = bk % K;
  __shared__ int s_idx[G][4];
  __shared__ float s_w[G][4];
  const int t = threadIdx.x;
  const int g = t >> 6, lane = t & 63;
  {
    const int n = b * G + g;
    float v = x2[((size_t)n * INTER + lane) * K + k] * gate[n * INTER + lane];
    float s = v, ss = v * v;
    for (int o = 32; o; o >>= 1) {
      s += __shfl_xor(s, o);
      ss += __shfl_xor(ss, o);
    }
    const float mean = s * (1.f / INTER);
    const float var = ss * (1.f / INTER) - mean * mean;
    const float xn = (v - mean) * rsqrtf(var + 1e-5f) * ln2w[lane] + ln2b[lane];
    float ox = xn * offw[lane];
    float oy = xn * offw[INTER + lane];
    for (int o = 32; o; o >>= 1) {
      ox += __shfl_xor(ox, o);
      oy += __shfl_xor(oy, o);
    }
    if (lane == 0) {
      const int yi = k / LR, xi = k % LR;
      const float rx = (xi + 0.5f) / 23.f * 2.f - 1.f;
      const float ry = (yi + 0.5f) / 23.f * 2.f - 1.f;
      const float px = tanhf(rx + ox), py = tanhf(ry + oy);
      const float x = (px + 1.f) * 0.5f * (HR - 1);
      const float y = (py + 1.f) * 0.5f * (HR - 1);
      const float x0f = floorf(x), y0f = floorf(y);
      const float wx = x - x0f, wy = y - y0f;
      const int x0 = min(max((int)x0f, 0), HR - 1);
      const int x1 = min(x0 + 1, HR - 1);
      const int y0 = min(max((int)y0f, 0), HR - 1);
      const int y1 = min(y0 + 1, HR - 1);
      s_idx[g][0] = y0 * HR + x0;
      s_idx[g][1] = y0 * HR + x1;
      s_idx[g][2] = y1 * HR + x0;
      s_idx[g][3] = y1 * HR + x1;
      s_w[g][0] = (1.f - wx) * (1.f - wy);
      s_w[g][1] = wx * (1.f - wy);
      s_w[g][2] = (1.f - wx) * wy;
      s_w[g][3] = wx * wy;
    }
  }
  __syncthreads();
  const int m = b * 576 + k;
  const int mb = m >> 6, fr = (m >> 4) & 3, r = m & 15;
  const int ch0 = t * 8;
  const int gg = ch0 >> 9;
  const float* ib = img + (size_t)b * HR * HR * C + ch0;
  float v[8];
#pragma unroll
  for (int j = 0; j < 8; ++j) v[j] = 0.f;
#pragma unroll
  for (int q = 0; q < 4; ++q) {
    const float wq_ = s_w[gg][q];
    const float* p = ib + (size_t)s_idx[gg][q] * C;
    const float4 a = *(const float4*)p;
    const float4 c = *(const float4*)(p + 4);
    v[0] += wq_ * a.x; v[1] += wq_ * a.y; v[2] += wq_ * a.z; v[3] += wq_ * a.w;
    v[4] += wq_ * c.x; v[5] += wq_ * c.y; v[6] += wq_ * c.z; v[7] += wq_ * c.w;
  }
  const int kb = ch0 >> 6, kc = (ch0 >> 5) & 1, ks3 = (ch0 >> 3) & 3;
  u16* dst = sampst + ((size_t)(mb * 32 + kb)) * 4096 +
             (((fr * 2 + kc) * 4 + ks3) * 16 + r) * 8;
  us4 o0, o1;
  o0.x = f2bf1(v[0]); o0.y = f2bf1(v[1]); o0.z = f2bf1(v[2]); o0.w = f2bf1(v[3]);
  o1.x = f2bf1(v[4]); o1.y = f2bf1(v[5]); o1.z = f2bf1(v[6]); o1.w = f2bf1(v[7]);
  *(us4*)dst = o0;
  *(us4*)(dst + 4) = o1;
}

// ---- unified MFMA flash attention, KVBLK=64 --------------------------------
__global__ __launch_bounds__(256) void attn_u64(
    const u16* __restrict__ qb, const u16* __restrict__ kg,
    const u16* __restrict__ vg, u16* __restrict__ aob_st) {
  const int i = blockIdx.x;  // 0..511
  const int pair = i & 255, half = i >> 8;
  const int bh = pair & 31;
  const int q8 = pair >> 5;
  const int qblk = half ? (15 - q8) : q8;
  const int b = bh >> 4, h = bh & 15;
  const int q0 = qblk * 64;
  const int tid = threadIdx.x, lane = tid & 63, w = tid >> 6;
  const int qw = q0 + w * 16;
  const int col = lane & 15, kpart = lane >> 4, rbase = kpart * 4;
  __shared__ u16 Ks[2][8192];
  __shared__ u16 Vs[2][8192];
  __shared__ u16 Pl[4][16 * 72];
  bf8 qf[4];
  {
    const u16* qp =
        qb + (size_t)(b * 1024 + qw + col) * 2048 + h * 128 + kpart * 8;
#pragma unroll
    for (int dc = 0; dc < 4; ++dc) qf[dc] = *(const bf8*)(qp + dc * 32);
  }
  f4 o[8];
#pragma unroll
  for (int df = 0; df < 8; ++df) o[df] = f4{0.f, 0.f, 0.f, 0.f};
  float m_r[4] = {-1e30f, -1e30f, -1e30f, -1e30f};
  float l_p[4] = {0.f, 0.f, 0.f, 0.f};
  const float scale = 0.08838834764831845f;
  const int nt_text = qblk + 1;
  const int nt = nt_text + 9;
  const u16* kbh = kg + (size_t)bh * (NKV * 128);
  const u16* vbh = vg + (size_t)bh * (NKV * 128);
  u16* pw = &Pl[w][0];

#define ASTG64(bi, kv0)                                                       \
  do {                                                                        \
    const u16* gk = kbh + (size_t)((kv0) >> 5) * 4096 + w * 2048 + lane * 8;  \
    GLDS(gk, &Ks[bi][w * 2048 + lane * 8]);                                   \
    GLDS(gk + 512, &Ks[bi][w * 2048 + 512 + lane * 8]);                       \
    GLDS(gk + 1024, &Ks[bi][w * 2048 + 1024 + lane * 8]);                     \
    GLDS(gk + 1536, &Ks[bi][w * 2048 + 1536 + lane * 8]);                     \
    const u16* gv = vbh + (size_t)((kv0) >> 3) * 1024 + w * 2048 + lane * 8;  \
    GLDS(gv, &Vs[bi][w * 2048 + lane * 8]);                                   \
    GLDS(gv + 512, &Vs[bi][w * 2048 + 512 + lane * 8]);                       \
    GLDS(gv + 1024, &Vs[bi][w * 2048 + 1024 + lane * 8]);                     \
    GLDS(gv + 1536, &Vs[bi][w * 2048 + 1536 + lane * 8]);                     \
  } while (0)

  ASTG64(0, 0);
  int cur = 0;
  for (int t = 0; t < nt; ++t) {
    const bool is_text = t < nt_text;
    const int kv0 = is_text ? (t << 6) : (1024 + ((t - nt_text) << 6));
    SB();
    if (t + 1 < nt) {
      const int t1 = t + 1;
      const int kv1 =
          (t1 < nt_text) ? (t1 << 6) : (1024 + ((t1 - nt_text) << 6));
      ASTG64(cur ^ 1, kv1);
      WVM(8);
    } else {
      WVM(0);
    }
    SB();
    const u16* ksb = &Ks[cur][0];
    const u16* vsb = &Vs[cur][0];
    f4 s0 = {0.f, 0.f, 0.f, 0.f}, s1 = {0.f, 0.f, 0.f, 0.f};
    f4 s2 = {0.f, 0.f, 0.f, 0.f}, s3 = {0.f, 0.f, 0.f, 0.f};
    __builtin_amdgcn_s_setprio(1);
#pragma unroll
    for (int dc = 0; dc < 4; ++dc) {
      const int dblk = dc * 4 + kpart;
      bf8 k0f = *(const bf8*)(ksb + (dblk * 32 + col) * 8);
      bf8 k1f = *(const bf8*)(ksb + (dblk * 32 + 16 + col) * 8);
      bf8 k2f = *(const bf8*)(ksb + 4096 + (dblk * 32 + col) * 8);
      bf8 k3f = *(const bf8*)(ksb + 4096 + (dblk * 32 + 16 + col) * 8);
      s0 = MFMA16(qf[dc], k0f, s0);
      s1 = MFMA16(qf[dc], k1f, s1);
      s2 = MFMA16(qf[dc], k2f, s2);
      s3 = MFMA16(qf[dc], k3f, s3);
    }
    __builtin_amdgcn_s_setprio(0);
    float sa[4][4], loc[4], p[4][4];
    bool grow = false;
    const bool need_mask = is_text && (kv0 + 63 > qw);
#pragma unroll
    for (int rr = 0; rr < 4; ++rr) {
      float a0 = s0[rr] * scale, a1 = s1[rr] * scale;
      float a2 = s2[rr] * scale, a3 = s3[rr] * scale;
      if (need_mask) {
        const int qg = qw + rbase + rr;
        if (kv0 + col > qg) a0 = -1e30f;
        if (kv0 + 16 + col > qg) a1 = -1e30f;
        if (kv0 + 32 + col > qg) a2 = -1e30f;
        if (kv0 + 48 + col > qg) a3 = -1e30f;
      }
      sa[rr][0] = a0; sa[rr][1] = a1; sa[rr][2] = a2; sa[rr][3] = a3;
      loc[rr] = fmaxf(fmaxf(a0, a1), fmaxf(a2, a3));
      grow |= (loc[rr] > m_r[rr] + 8.f);
    }
    if (__any(grow)) {
      float fr[4];
#pragma unroll
      for (int rr = 0; rr < 4; ++rr) {
        float mx = loc[rr];
        mx = fmaxf(mx, __shfl_xor(mx, 1));
        mx = fmaxf(mx, __shfl_xor(mx, 2));
        mx = fmaxf(mx, __shfl_xor(mx, 4));
        mx = fmaxf(mx, __shfl_xor(mx, 8));
        const float mn = fmaxf(m_r[rr], mx);
        fr[rr] = __expf(m_r[rr] - mn);
        m_r[rr] = mn;
#pragma unroll
        for (int jj = 0; jj < 4; ++jj) p[rr][jj] = __expf(sa[rr][jj] - mn);
        l_p[rr] = l_p[rr] * fr[rr] + p[rr][0] + p[rr][1] + p[rr][2] + p[rr][3];
      }
#pragma unroll
      for (int df = 0; df < 8; ++df) {
        o[df][0] *= fr[0]; o[df][1] *= fr[1];
        o[df][2] *= fr[2]; o[df][3] *= fr[3];
      }
    } else {
#pragma unroll
      for (int rr = 0; rr < 4; ++rr) {
#pragma unroll
        for (int jj = 0; jj < 4; ++jj) p[rr][jj] = __expf(sa[rr][jj] - m_r[rr]);
        l_p[rr] += p[rr][0] + p[rr][1] + p[rr][2] + p[rr][3];
      }
    }
#pragma unroll
    for (int rr = 0; rr < 4; ++rr) {
      pw[(rbase + rr) * 72 + col] = f2bf1(p[rr][0]);
      pw[(rbase + rr) * 72 + 16 + col] = f2bf1(p[rr][1]);
      pw[(rbase + rr) * 72 + 32 + col] = f2bf1(p[rr][2]);
      pw[(rbase + rr) * 72 + 48 + col] = f2bf1(p[rr][3]);
    }
    bf8 pa0 = *(const bf8*)(pw + col * 72 + kpart * 8);
    bf8 pa1 = *(const bf8*)(pw + col * 72 + 32 + kpart * 8);
    __builtin_amdgcn_s_setprio(1);
#pragma unroll
    for (int df = 0; df < 8; ++df) {
      bf8 vf0 = *(const bf8*)(vsb + (kpart * 128 + df * 16 + col) * 8);
      bf8 vf1 = *(const bf8*)(vsb + ((kpart + 4) * 128 + df * 16 + col) * 8);
      o[df] = MFMA16(pa0, vf0, o[df]);
      o[df] = MFMA16(pa1, vf1, o[df]);
    }
    __builtin_amdgcn_s_setprio(0);
    cur ^= 1;
  }
#undef ASTG64
  float inv[4];
#pragma unroll
  for (int rr = 0; rr < 4; ++rr) {
    float ps = l_p[rr];
    ps += __shfl_xor(ps, 1);
    ps += __shfl_xor(ps, 2);
    ps += __shfl_xor(ps, 4);
    ps += __shfl_xor(ps, 8);
    inv[rr] = 1.f / ps;
  }
#pragma unroll
  for (int rr = 0; rr < 4; ++rr) {
    const int m = b * 1024 + qw + rbase + rr;
    const int mb = m >> 6, fr3 = (m >> 4) & 3, r16 = m & 15;
#pragma unroll
    for (int df = 0; df < 8; ++df) {
      const int ncol = h * 128 + df * 16 + col;
      const int kb = ncol >> 6, kc = (ncol >> 5) & 1, ks3 = (ncol >> 3) & 3,
                j0 = ncol & 7;
      aob_st[((size_t)(mb * 32 + kb)) * 4096 +
             (((fr3 * 2 + kc) * 4 + ks3) * 16 + r16) * 8 + j0] =
          f2bf1(o[df][rr] * inv[rr]);
    }
  }
}

// ---------------------------------------------------------------------------
extern "C" void kernel_launch(void* const* d_in, const int* in_sizes, int n_in,
                              void* d_out, int out_size, void* d_ws,
                              size_t ws_size, hipStream_t stream) {
  const float* hs = (const float*)d_in[0];
  const float* img = (const float*)d_in[1];
  const float* wq = (const float*)d_in[2];
  const float* wk = (const float*)d_in[3];
  const float* wv = (const float*)d_in[4];
  const float* wo = (const float*)d_in[5];
  const float* cdw = (const float*)d_in[6];
  const float* ln1w = (const float*)d_in[7];
  const float* ln1b = (const float*)d_in[8];
  const float* plrw = (const float*)d_in[9];
  const float* piw = (const float*)d_in[10];
  const float* pib = (const float*)d_in[11];
  const float* ln2w = (const float*)d_in[12];
  const float* ln2b = (const float*)d_in[13];
  const float* offw = (const float*)d_in[14];
  const float* khw = (const float*)d_in[15];
  const float* khb = (const float*)d_in[16];
  const float* vhw = (const float*)d_in[17];
  const float* vhb = (const float*)d_in[18];
  float* outp = (float*)d_out;

  u16* wsp = (u16*)d_ws;
  const size_t SZ = 4194304;  // 2048*2048
  u16* hs_st = wsp;
  u16* wq_st = wsp + SZ;       // reused as aob_st after gemm
  u16* wk_st = wsp + 2 * SZ;
  u16* wv_st = wsp + 3 * SZ;
  u16* wo_st = wsp + 4 * SZ;   // live until gemm_out3
  u16* khw_st = wsp + 5 * SZ;
  u16* vhw_st = wsp + 6 * SZ;
  u16* qb_bf = wsp + 7 * SZ;
  u16* samp_st = wsp + 8 * SZ;       // 1152*2048 staged
  u16* kg = wsp + 8 * SZ + 2359296;  // 2*16*1600*128
  u16* vg = kg + 6553600;
  // fp32 scratch overlays kg/vg (dead before gemms)
  float* x1b = (float*)kg + 2359296;
  float* x2b = x1b + 2359296;
  float* poolb = x2b + 294912;
  float* gb = poolb + 4096;
  float* wtb = (float*)(vg + 6553600);  // 32768 floats, persistent
  u16* aob_st = wq_st;

  dim3 blk(256);
  // L1: conversions (staged) + plrw^T + dwconv/pool, one launch
  f2bf_k9b<<<dim3(1024, 9), blk, 0, stream>>>(
      hs, wq, wk, wv, wo, khw, vhw, plrw, cdw, hs_st, wq_st, wk_st, wv_st,
      wo_st, khw_st, vhw_st, wtb, x1b, poolb);
  // L2: LN(512) + 1x1 conv + gate
  lnproj_gate<<<dim3(74), blk, 0, stream>>>(x1b, ln1w, ln1b, wtb, poolb, piw,
                                            pib, x2b, gb);
  // L3: LN(64)+offsets+tanh + bilinear sample -> staged samp
  pos_sample<<<dim3(B * K), blk, 0, stream>>>(x2b, gb, ln2w, ln2b, offw, img,
                                              samp_st);
  // L4a: HD k/v single-tile GEMM (288 blocks, 48KB LDS -> 3 blocks/CU)
  gemm_hd1<<<dim3(288), dim3(512), 0, stream>>>(samp_st, khw_st, vhw_st, khb,
                                                vhb, kg, vg);
  // L4b: QKV 256^2 8-phase (192 blocks, static XCD swizzle)
  gemm256<<<dim3(192), dim3(512), 0, stream>>>(hs_st, wq_st, wk_st, wv_st,
                                               qb_bf, kg, vg);
  // L5: unified attention, KVBLK=64 (writes staged aob)
  attn_u64<<<dim3(512), blk, 0, stream>>>(qb_bf, kg, vg, aob_st);
  // L6: output projection (256 blocks, 3-deep pipeline)
  gemm_out3<<<dim3(256), blk, 0, stream>>>(aob_st, wo_st, outp);
}

// Round 17
// 319.598 us; speedup vs baseline: 1.0349x; 1.0349x over previous
//
#include <hip/hip_runtime.h>

typedef unsigned short u16;
typedef unsigned int u32;
typedef __attribute__((ext_vector_type(8))) short bf8;
typedef __attribute__((ext_vector_type(4))) float f4;
typedef __attribute__((ext_vector_type(4))) unsigned short us4;

constexpr int B = 2;
constexpr int NQ = 1024;
constexpr int C = 2048;
constexpr int DH = 128;
constexpr int G = 4;
constexpr int CD = 512;
constexpr int LR = 24;
constexpr int HR = 72;
constexpr int INTER = 64;
constexpr int K = LR * LR;  // 576
constexpr int NKV = NQ + K; // 1600

#define MFMA16(a, b, c) __builtin_amdgcn_mfma_f32_16x16x32_bf16(a, b, c, 0, 0, 0)
#define GLDS(g, l)                                                         \
  __builtin_amdgcn_global_load_lds(                                        \
      (const __attribute__((address_space(1))) void*)(g),                  \
      (__attribute__((address_space(3))) void*)(l), 16, 0, 0)
#define SB()                               \
  do {                                     \
    __builtin_amdgcn_sched_barrier(0);     \
    __builtin_amdgcn_s_barrier();          \
    __builtin_amdgcn_sched_barrier(0);     \
  } while (0)
#define WVM(n)                                              \
  do {                                                      \
    asm volatile("s_waitcnt vmcnt(" #n ")" ::: "memory");   \
    __builtin_amdgcn_sched_barrier(0);                      \
  } while (0)

__device__ __forceinline__ u16 f2bf1(float f) {
  u32 u = __float_as_uint(f);
  u32 r = (u + 0x7fffu + ((u >> 16) & 1u)) >> 16;
  return (u16)r;
}

// ---- conversions: fp32->bf16 STAGED (7 tensors) + plrw^T (8.7KB LDS) -------
__global__ __launch_bounds__(256) void f2bf_k8v(
    const float* __restrict__ s0, const float* __restrict__ s1,
    const float* __restrict__ s2, const float* __restrict__ s3,
    const float* __restrict__ s4, const float* __restrict__ s5,
    const float* __restrict__ s6, const float* __restrict__ plrw,
    u16* __restrict__ d0, u16* __restrict__ d1, u16* __restrict__ d2,
    u16* __restrict__ d3, u16* __restrict__ d4, u16* __restrict__ d5,
    u16* __restrict__ d6, float* __restrict__ wt) {
  __shared__ u16 L[64 * 68];  // 8.7 KB -> 8 blocks/CU
  const int y = blockIdx.y;
  const int t = threadIdx.x;
  if (y == 7) {
    if (blockIdx.x >= 128) return;
    const int idx = blockIdx.x * 256 + t;
    wt[idx] = plrw[(idx & 63) * 512 + (idx >> 6)];
    return;
  }
  const float* s;
  u16* d;
  switch (y) {
    case 0: s = s0; d = d0; break;
    case 1: s = s1; d = d1; break;
    case 2: s = s2; d = d2; break;
    case 3: s = s3; d = d3; break;
    case 4: s = s4; d = d4; break;
    case 5: s = s5; d = d5; break;
    default: s = s6; d = d6; break;
  }
  const int pc = blockIdx.x;
  const int mb = pc >> 5, kb = pc & 31;
  const int rin = t >> 2, c0 = (t & 3) * 16;
  const float* src = s + (size_t)(mb * 64 + rin) * 2048 + kb * 64 + c0;
#pragma unroll
  for (int j = 0; j < 16; j += 4) {
    float4 v = *(const float4*)(src + j);
    L[rin * 68 + c0 + j] = f2bf1(v.x);
    L[rin * 68 + c0 + j + 1] = f2bf1(v.y);
    L[rin * 68 + c0 + j + 2] = f2bf1(v.z);
    L[rin * 68 + c0 + j + 3] = f2bf1(v.w);
  }
  __syncthreads();
  u16* dst = d + (size_t)pc * 4096 + t * 16;
#pragma unroll
  for (int gg = 0; gg < 2; ++gg) {
    const int g = t * 2 + gg;
    const int rh = g & 15, ks2 = (g >> 4) & 3, kc = (g >> 6) & 1, fr = g >> 7;
    const int row = fr * 16 + rh, cc = kc * 32 + ks2 * 8;
    us4 o0, o1;
    o0.x = L[row * 68 + cc];     o0.y = L[row * 68 + cc + 1];
    o0.z = L[row * 68 + cc + 2]; o0.w = L[row * 68 + cc + 3];
    o1.x = L[row * 68 + cc + 4]; o1.y = L[row * 68 + cc + 5];
    o1.z = L[row * 68 + cc + 6]; o1.w = L[row * 68 + cc + 7];
    *(us4*)(dst + gg * 8) = o0;
    *(us4*)(dst + gg * 8 + 4) = o1;
  }
}

// ---- dwconv3x3+silu+pool, 16 channels/block (36.9 KB LDS, 256 blocks) ------
__global__ __launch_bounds__(256) void dwpool16(const float* __restrict__ hs,
                                                const float* __restrict__ cdw,
                                                float* __restrict__ x1,
                                                float* __restrict__ pooled) {
  __shared__ float SH[16 * 577];
  const int bidx = blockIdx.x;  // n*32 + cg
  const int n = bidx >> 5, cg = bidx & 31;
  const int b = n >> 2, g = n & 3;
  const int c0 = cg * 16;
  const int t = threadIdx.x;
  {
    const int c = t & 15, pr = t >> 4;
    const float* src = hs + (size_t)b * 1024 * 2048 + g * 512 + c0 + c;
#pragma unroll 4
    for (int j = 0; j < 36; ++j) {
      const int p = j * 16 + pr;
      SH[c * 577 + p] = src[(size_t)p * 2048];
    }
  }
  __syncthreads();
  {
    const int c = t >> 4, seg = t & 15;
    float s = 0.f;
    for (int i = 0; i < 36; ++i) s += SH[c * 577 + seg * 36 + i];
    s += __shfl_xor(s, 1);
    s += __shfl_xor(s, 2);
    s += __shfl_xor(s, 4);
    s += __shfl_xor(s, 8);
    if (seg == 0) pooled[n * 512 + c0 + c] = s * (1.f / 576.f);
  }
  const size_t base_out = (size_t)(n * 512 + c0) * 576;
  for (int j = 0; j < 36; ++j) {
    const int idx = j * 256 + t;
    const int c = idx / 576, p = idx - c * 576;
    const int yy0 = p / 24, xx0 = p - yy0 * 24;
    const float* wp = cdw + (c0 + c) * 9;
    float s = 0.f;
#pragma unroll
    for (int dy = -1; dy <= 1; ++dy)
#pragma unroll
      for (int dx = -1; dx <= 1; ++dx) {
        const int yy = yy0 + dy, xx = xx0 + dx;
        if (yy < 0 || yy >= 24 || xx < 0 || xx >= 24) continue;
        s += SH[c * 577 + yy * 24 + xx] * wp[(dy + 1) * 3 + dx + 1];
      }
    x1[base_out + idx] = s / (1.f + expf(-s));
  }
}

// ---- persistent work-queue GEMM: 256 blocks pull 480 tiles -----------------
// items 0..191: QKV 256^2 8-phase; items 192..479: HD single 128^2 (fine).
__global__ __launch_bounds__(512, 2) void gemm_queue(
    const u16* __restrict__ Ast, const u16* __restrict__ Wq,
    const u16* __restrict__ Wk, const u16* __restrict__ Wv,
    const u16* __restrict__ sampst, const u16* __restrict__ khwst,
    const u16* __restrict__ vhwst, const float* __restrict__ khb,
    const float* __restrict__ vhb, u16* __restrict__ outq,
    u16* __restrict__ kg, u16* __restrict__ vg, u32* __restrict__ qctr) {
  __shared__ u16 As[2][4][4096];
  __shared__ u16 Bs[2][4][4096];
  __shared__ int s_item;
  const int tid = threadIdx.x, lane = tid & 63, w = tid >> 6;
  const int ks = lane >> 4, r = lane & 15;

  while (true) {
    __syncthreads();  // separates prior item's epilogue from fetch + staging
    if (tid == 0) s_item = (int)atomicAdd(qctr, 1u);
    __syncthreads();
    const int item = s_item;
    if (item >= 480) break;

    if (item < 192) {
      // ===================== QKV 256x256 8-phase =========================
      const int wm = w >> 2, wn = w & 3;
      const int swz = (item & 7) * 24 + (item >> 3);
      const int mt = swz / 24, nt = swz % 24;
      const u16* Wst = (nt < 8) ? Wq : (nt < 16) ? Wk : Wv;
      const int nb0 = (nt & 7) * 4;
      const int mb0 = mt * 4;

#define ST_A03(bi, kt)                                                        \
  do {                                                                        \
    GLDS(Ast + ((size_t)(mb0 + 0) * 32 + (kt)) * 4096 + tid * 8,              \
         &As[bi][0][tid * 8]);                                                \
    GLDS(Ast + ((size_t)(mb0 + 2) * 32 + (kt)) * 4096 + tid * 8,              \
         &As[bi][2][tid * 8]);                                                \
  } while (0)
#define ST_A47(bi, kt)                                                        \
  do {                                                                        \
    GLDS(Ast + ((size_t)(mb0 + 1) * 32 + (kt)) * 4096 + tid * 8,              \
         &As[bi][1][tid * 8]);                                                \
    GLDS(Ast + ((size_t)(mb0 + 3) * 32 + (kt)) * 4096 + tid * 8,              \
         &As[bi][3][tid * 8]);                                                \
  } while (0)
#define ST_B01(bi, kt)                                                        \
  do {                                                                        \
    GLDS(Wst + ((size_t)(nb0 + 0) * 32 + (kt)) * 4096 + tid * 8,              \
         &Bs[bi][0][tid * 8]);                                                \
    GLDS(Wst + ((size_t)(nb0 + 1) * 32 + (kt)) * 4096 + tid * 8,              \
         &Bs[bi][1][tid * 8]);                                                \
  } while (0)
#define ST_B23(bi, kt)                                                        \
  do {                                                                        \
    GLDS(Wst + ((size_t)(nb0 + 2) * 32 + (kt)) * 4096 + tid * 8,              \
         &Bs[bi][2][tid * 8]);                                                \
    GLDS(Wst + ((size_t)(nb0 + 3) * 32 + (kt)) * 4096 + tid * 8,              \
         &Bs[bi][3][tid * 8]);                                                \
  } while (0)
#define RD_A(dst, bi, half, kc)                                               \
  _Pragma("unroll") for (int i2 = 0; i2 < 4; ++i2) dst[i2] =                  \
      *(const bf8*)(&As[bi][wm * 2 + (half)]                                  \
                       [((i2 * 2 + (kc)) * 4 + ks) * 128 + r * 8]);
#define RD_B(dst, bi, kc)                                                     \
  _Pragma("unroll") for (int j2 = 0; j2 < 4; ++j2) dst[j2] =                  \
      *(const bf8*)(&Bs[bi][wn][((j2 * 2 + (kc)) * 4 + ks) * 128 + r * 8]);
#define MM(ACC, AF, BF)                                                       \
  do {                                                                        \
    __builtin_amdgcn_s_setprio(1);                                            \
    _Pragma("unroll") for (int i3 = 0; i3 < 4; ++i3)                          \
        _Pragma("unroll") for (int j3 = 0; j3 < 4; ++j3) ACC[i3][j3] =        \
            MFMA16(AF[i3], BF[j3], ACC[i3][j3]);                              \
    __builtin_amdgcn_s_setprio(0);                                            \
  } while (0)

      f4 accA[4][4], accB[4][4];
#pragma unroll
      for (int i = 0; i < 4; ++i)
#pragma unroll
        for (int j = 0; j < 4; ++j) {
          accA[i][j] = f4{0.f, 0.f, 0.f, 0.f};
          accB[i][j] = f4{0.f, 0.f, 0.f, 0.f};
        }
      bf8 af[4], b0[4], b1[4];

      ST_A03(0, 0); ST_B01(0, 0); ST_B23(0, 0); ST_A47(0, 0);
      ST_A03(1, 1); ST_B01(1, 1);
      WVM(6);
      SB();

      for (int t = 0; t < 32; ++t) {
        const int buf = t & 1;
        RD_A(af, buf, 0, 0);
        RD_B(b0, buf, 0);
        if (t + 1 < 32) ST_B23(buf ^ 1, t + 1);
        SB();
        MM(accA, af, b0);
        SB();
        RD_A(af, buf, 0, 1);
        RD_B(b1, buf, 1);
        if (t + 1 < 32) ST_A47(buf ^ 1, t + 1);
        SB();
        MM(accA, af, b1);
        if (t + 1 < 32) { WVM(8); } else { WVM(0); }
        SB();
        RD_A(af, buf, 1, 0);
        if (t + 2 < 32) ST_A03(buf, t + 2);
        SB();
        MM(accB, af, b0);
        SB();
        RD_A(af, buf, 1, 1);
        if (t + 2 < 32) ST_B01(buf, t + 2);
        SB();
        MM(accB, af, b1);
        if (t + 2 < 32) { WVM(6); } else if (t + 1 < 32) { WVM(2); }
        SB();
      }

#define EPI(ACC, HALF)                                                        \
  _Pragma("unroll") for (int i = 0; i < 4; ++i)                               \
      _Pragma("unroll") for (int j = 0; j < 4; ++j)                           \
          _Pragma("unroll") for (int rr = 0; rr < 4; ++rr) {                  \
    const int m = mt * 256 + wm * 128 + (HALF)*64 + i * 16 + ks * 4 + rr;     \
    const int n = nt * 256 + wn * 64 + j * 16 + r;                            \
    const float v = ACC[i][j][rr];                                            \
    const int sel = n >> 11, nn = n & 2047, hh = nn >> 7, dd = nn & 127;      \
    const int bb = m >> 10, qq = m & 1023;                                    \
    const u16 bv = f2bf1(v);                                                  \
    if (sel == 0) {                                                           \
      outq[(size_t)m * 2048 + nn] = bv;                                       \
    } else if (sel == 1) {                                                    \
      kg[(((size_t)(bb * 16 + hh) * 50 + (qq >> 5)) * 16 + (dd >> 3)) * 256 + \
         (qq & 31) * 8 + (dd & 7)] = bv;                                      \
    } else {                                                                  \
      vg[((size_t)(bb * 16 + hh) * 200 + (qq >> 3)) * 1024 + dd * 8 +         \
         (qq & 7)] = bv;                                                      \
    }                                                                         \
  }
      EPI(accA, 0)
      EPI(accB, 1)
#undef EPI
    } else {
      // ==== HD single 128^2: 8 waves (wr=w>>2 x wc=w&3), 2-deep pipeline ====
      u16* A3 = &As[0][0][0];  // 3 x 4096
      u16* B3 = &Bs[0][0][0];  // 3 x 4096
      const int htile = item - 192;  // 0..287
      const bool is_v = (htile >= 144);
      const int hb = is_v ? (htile - 144) : htile;
      const int mt = hb / 16, nt = hb % 16;
      const int ma0 = mt * 2, nb0 = nt * 2;
      const int wr = w >> 2, wc = w & 3;
      const u16* Wsrc = is_v ? vhwst : khwst;

#define HDS1(bi, kt)                                                          \
  do {                                                                        \
    const int kb_ = (kt) >> 1, kc_ = (kt) & 1;                                \
    GLDS(sampst + ((size_t)(ma0 + (w >> 2)) * 32 + kb_) * 4096 +              \
             (w & 3) * 1024 + kc_ * 512 + lane * 8,                           \
         &A3[(bi)*4096 + w * 512 + lane * 8]);                                \
    GLDS(Wsrc + ((size_t)(nb0 + (w >> 2)) * 32 + kb_) * 4096 +                \
             (w & 3) * 1024 + kc_ * 512 + lane * 8,                           \
         &B3[(bi)*4096 + w * 512 + lane * 8]);                                \
  } while (0)

      f4 acc[4][2];
#pragma unroll
      for (int i = 0; i < 4; ++i)
#pragma unroll
        for (int j = 0; j < 2; ++j) acc[i][j] = f4{0.f, 0.f, 0.f, 0.f};

      HDS1(0, 0);
      HDS1(1, 1);
      int rd = 0;
      for (int kt = 0; kt < 64; ++kt) {
        SB();  // B1: closes iter kt-1's LDS reads
        if (kt + 2 < 64) {
          const int wb = (rd + 2 >= 3) ? rd - 1 : rd + 2;
          HDS1(wb, kt + 2);
          WVM(4);  // my 2 loads for tile kt landed
        } else if (kt + 1 < 64) {
          WVM(2);
        } else {
          WVM(0);
        }
        SB();  // B2: all waves' tile-kt loads landed
        bf8 af2[4], bw[2];
#pragma unroll
        for (int i = 0; i < 4; ++i)
          af2[i] = *(const bf8*)(&A3[rd * 4096 + (wr * 4 + i) * 512 +
                                     ks * 128 + r * 8]);
#pragma unroll
        for (int j = 0; j < 2; ++j)
          bw[j] = *(const bf8*)(&B3[rd * 4096 + (wc * 2 + j) * 512 +
                                    ks * 128 + r * 8]);
        __builtin_amdgcn_s_setprio(1);
#pragma unroll
        for (int i = 0; i < 4; ++i)
#pragma unroll
          for (int j = 0; j < 2; ++j)
            acc[i][j] = MFMA16(af2[i], bw[j], acc[i][j]);
        __builtin_amdgcn_s_setprio(0);
        rd = (rd + 1 >= 3) ? 0 : rd + 1;
      }
#undef HDS1
      const int rbase = ks * 4;
      const float* bias = is_v ? vhb : khb;
#pragma unroll
      for (int i = 0; i < 4; ++i)
#pragma unroll
        for (int j = 0; j < 2; ++j) {
          const int nn = nt * 128 + (wc * 2 + j) * 16 + r;
          const int hh = nn >> 7, dd = nn & 127;
#pragma unroll
          for (int rr = 0; rr < 4; ++rr) {
            const int m = mt * 128 + wr * 64 + i * 16 + rbase + rr;
            const int bb = m / 576;
            const int kv = 1024 + (m - bb * 576);
            const u16 bv = f2bf1(acc[i][j][rr] + bias[nn]);
            if (!is_v) {
              kg[(((size_t)(bb * 16 + hh) * 50 + (kv >> 5)) * 16 + (dd >> 3)) *
                     256 +
                 (kv & 31) * 8 + (dd & 7)] = bv;
            } else {
              vg[((size_t)(bb * 16 + hh) * 200 + (kv >> 3)) * 1024 + dd * 8 +
                 (kv & 7)] = bv;
            }
          }
        }
    }
  }
}

// ---- output projection: staged x staged, 3-buffer 2-deep pipeline ----------
__global__ __launch_bounds__(256) void gemm_out3(const u16* __restrict__ Ast,
                                                 const u16* __restrict__ W0,
                                                 float* __restrict__ outf) {
  __shared__ u16 As[3][4096];
  __shared__ u16 Bs[3][4096];
  const int tid = threadIdx.x, lane = tid & 63, w = tid >> 6;
  const int wr = w >> 1, wc = w & 1;
  const int ksl = lane >> 4, rl = lane & 15;
  const int xcd = blockIdx.x & 7, idx = blockIdx.x >> 3;
  const int mt = (xcd >> 2) * 8 + idx / 4;
  const int nt = (xcd & 3) * 4 + idx % 4;
  const u16* Wp = W0;
  const int ma0 = mt * 2;
  const int nb0 = nt * 2;

#define GST2(dstArr, srcBase, tb0, kt)                                     \
  do {                                                                     \
    const int kb_ = (kt) >> 1, kc_ = (kt) & 1;                             \
    _Pragma("unroll") for (int r2 = 0; r2 < 2; ++r2) {                     \
      const int run = r2 * 4 + w;                                          \
      GLDS(srcBase + ((size_t)((tb0) + (run >> 2)) * 32 + kb_) * 4096 +    \
               (run & 3) * 1024 + kc_ * 512 + lane * 8,                    \
           &dstArr[run * 512 + lane * 8]);                                 \
    }                                                                      \
  } while (0)

  f4 acc[4][4];
#pragma unroll
  for (int i = 0; i < 4; ++i)
#pragma unroll
    for (int j = 0; j < 4; ++j) acc[i][j] = f4{0.f, 0.f, 0.f, 0.f};

  GST2(As[0], Ast, ma0, 0);
  GST2(Bs[0], Wp, nb0, 0);
  GST2(As[1], Ast, ma0, 1);
  GST2(Bs[1], Wp, nb0, 1);
  int rd = 0;
  for (int kt = 0; kt < 64; ++kt) {
    SB();
    if (kt + 2 < 64) {
      const int wb = (rd + 2 >= 3) ? rd - 1 : rd + 2;
      GST2(As[wb], Ast, ma0, kt + 2);
      GST2(Bs[wb], Wp, nb0, kt + 2);
      WVM(8);
    } else if (kt + 1 < 64) {
      WVM(4);
    } else {
      WVM(0);
    }
    SB();
    bf8 af[4], bw[4];
#pragma unroll
    for (int i = 0; i < 4; ++i)
      af[i] = *(const bf8*)(&As[rd][(wr * 4 + i) * 512 + ksl * 128 + rl * 8]);
#pragma unroll
    for (int j = 0; j < 4; ++j)
      bw[j] = *(const bf8*)(&Bs[rd][(wc * 4 + j) * 512 + ksl * 128 + rl * 8]);
    __builtin_amdgcn_s_setprio(1);
#pragma unroll
    for (int i = 0; i < 4; ++i)
#pragma unroll
      for (int j = 0; j < 4; ++j)
        acc[i][j] = MFMA16(af[i], bw[j], acc[i][j]);
    __builtin_amdgcn_s_setprio(0);
    rd = (rd + 1 >= 3) ? 0 : rd + 1;
  }
#undef GST2

  const int rbase = ksl * 4;
#pragma unroll
  for (int i = 0; i < 4; ++i)
#pragma unroll
    for (int j = 0; j < 4; ++j) {
      const int n = nt * 128 + wc * 64 + j * 16 + rl;
#pragma unroll
      for (int rr = 0; rr < 4; ++rr) {
        const int m = mt * 128 + wr * 64 + i * 16 + rbase + rr;
        outf[(size_t)m * 2048 + n] = acc[i][j][rr];
      }
    }
}

// -------------- offset network: fused LN(512)+1x1conv + gate ----------------
__global__ __launch_bounds__(256) void lnproj_gate(
    const float* __restrict__ x1, const float* __restrict__ ln1w,
    const float* __restrict__ ln1b, const float* __restrict__ wt,
    const float* __restrict__ pooled, const float* __restrict__ piw,
    const float* __restrict__ pib, float* __restrict__ x2,
    float* __restrict__ gate) {
  __shared__ float Xs[512][68];
  __shared__ float rs[4][64], rss[4][64];
  const int bidx = blockIdx.x;
  const int t = threadIdx.x;
  if (bidx >= 72) {
    const int idx = (bidx - 72) * 256 + t;
    const int n = idx >> 6, o = idx & 63;
    const float* pb = pooled + n * 512;
    const float* wb = piw + o * 512;
    float s = pib[o];
    for (int c = 0; c < 512; ++c) s += pb[c] * wb[c];
    gate[idx] = 1.f / (1.f + expf(-s));
    return;
  }
  const int n = bidx / 9, pc = bidx % 9;
  const int p0 = pc * 64;
  {
    const int pl = t & 63, c4 = t >> 6;
    const float* src = x1 + (size_t)n * 512 * 576 + p0 + pl;
#pragma unroll 4
    for (int j = 0; j < 128; ++j) {
      const int c = j * 4 + c4;
      Xs[c][pl] = src[(size_t)c * 576];
    }
  }
  __syncthreads();
  {
    const int pl = t & 63, q = t >> 6;
    float s = 0.f, ss = 0.f;
    for (int c = q * 128; c < q * 128 + 128; ++c) {
      const float v = Xs[c][pl];
      s += v;
      ss += v * v;
    }
    rs[q][pl] = s;
    rss[q][pl] = ss;
    __syncthreads();
    const float S = rs[0][pl] + rs[1][pl] + rs[2][pl] + rs[3][pl];
    const float SS = rss[0][pl] + rss[1][pl] + rss[2][pl] + rss[3][pl];
    const float mean = S * (1.f / 512.f);
    const float inv = rsqrtf(SS * (1.f / 512.f) - mean * mean + 1e-5f);
    for (int c = q * 128; c < q * 128 + 128; ++c)
      Xs[c][pl] = (Xs[c][pl] - mean) * inv * ln1w[c] + ln1b[c];
  }
  __syncthreads();
  {
    const int o4 = (t & 15) * 4, pl0 = (t >> 4) * 4;
    float acc[4][4] = {};
    for (int c = 0; c < 512; ++c) {
      const f4 xv = *(const f4*)(&Xs[c][pl0]);
      const f4 wv = *(const f4*)(&wt[c * 64 + o4]);
#pragma unroll
      for (int i = 0; i < 4; ++i)
#pragma unroll
        for (int j = 0; j < 4; ++j) acc[i][j] += wv[i] * xv[j];
    }
#pragma unroll
    for (int i = 0; i < 4; ++i) {
      f4 ov;
      ov[0] = acc[i][0]; ov[1] = acc[i][1];
      ov[2] = acc[i][2]; ov[3] = acc[i][3];
      *(f4*)(&x2[(size_t)(n * 64 + o4 + i) * 576 + p0 + pl0]) = ov;
    }
  }
}

// ------- fused: LN(64)+offsets+tanh positions + bilinear sample -> STAGED ---
__global__ __launch_bounds__(256) void pos_sample(
    const float* __restrict__ x2, const float* __restrict__ gate,
    const float* __restrict__ ln2w, const float* __restrict__ ln2b,
    const float* __restrict__ offw, const float* __restrict__ img,
    u16* __restrict__ sampst) {
  const int bk = blockIdx.x;
  const int b = bk / K, k = bk % K;
  __shared__ int s_idx[G][4];
  __shared__ float s_w[G][4];
  const int t = threadIdx.x;
  const int g = t >> 6, lane = t & 63;
  {
    const int n = b * G + g;
    float v = x2[((size_t)n * INTER + lane) * K + k] * gate[n * INTER + lane];
    float s = v, ss = v * v;
    for (int o = 32; o; o >>= 1) {
      s += __shfl_xor(s, o);
      ss += __shfl_xor(ss, o);
    }
    const float mean = s * (1.f / INTER);
    const float var = ss * (1.f / INTER) - mean * mean;
    const float xn = (v - mean) * rsqrtf(var + 1e-5f) * ln2w[lane] + ln2b[lane];
    float ox = xn * offw[lane];
    float oy = xn * offw[INTER + lane];
    for (int o = 32; o; o >>= 1) {
      ox += __shfl_xor(ox, o);
      oy += __shfl_xor(oy, o);
    }
    if (lane == 0) {
      const int yi = k / LR, xi = k % LR;
      const float rx = (xi + 0.5f) / 23.f * 2.f - 1.f;
      const float ry = (yi + 0.5f) / 23.f * 2.f - 1.f;
      const float px = tanhf(rx + ox), py = tanhf(ry + oy);
      const float x = (px + 1.f) * 0.5f * (HR - 1);
      const float y = (py + 1.f) * 0.5f * (HR - 1);
      const float x0f = floorf(x), y0f = floorf(y);
      const float wx = x - x0f, wy = y - y0f;
      const int x0 = min(max((int)x0f, 0), HR - 1);
      const int x1 = min(x0 + 1, HR - 1);
      const int y0 = min(max((int)y0f, 0), HR - 1);
      const int y1 = min(y0 + 1, HR - 1);
      s_idx[g][0] = y0 * HR + x0;
      s_idx[g][1] = y0 * HR + x1;
      s_idx[g][2] = y1 * HR + x0;
      s_idx[g][3] = y1 * HR + x1;
      s_w[g][0] = (1.f - wx) * (1.f - wy);
      s_w[g][1] = wx * (1.f - wy);
      s_w[g][2] = (1.f - wx) * wy;
      s_w[g][3] = wx * wy;
    }
  }
  __syncthreads();
  const int m = b * 576 + k;
  const int mb = m >> 6, fr = (m >> 4) & 3, r = m & 15;
  const int ch0 = t * 8;
  const int gg = ch0 >> 9;
  const float* ib = img + (size_t)b * HR * HR * C + ch0;
  float v[8];
#pragma unroll
  for (int j = 0; j < 8; ++j) v[j] = 0.f;
#pragma unroll
  for (int q = 0; q < 4; ++q) {
    const float wq_ = s_w[gg][q];
    const float* p = ib + (size_t)s_idx[gg][q] * C;
    const float4 a = *(const float4*)p;
    const float4 c = *(const float4*)(p + 4);
    v[0] += wq_ * a.x; v[1] += wq_ * a.y; v[2] += wq_ * a.z; v[3] += wq_ * a.w;
    v[4] += wq_ * c.x; v[5] += wq_ * c.y; v[6] += wq_ * c.z; v[7] += wq_ * c.w;
  }
  const int kb = ch0 >> 6, kc = (ch0 >> 5) & 1, ks3 = (ch0 >> 3) & 3;
  u16* dst = sampst + ((size_t)(mb * 32 + kb)) * 4096 +
             (((fr * 2 + kc) * 4 + ks3) * 16 + r) * 8;
  us4 o0, o1;
  o0.x = f2bf1(v[0]); o0.y = f2bf1(v[1]); o0.z = f2bf1(v[2]); o0.w = f2bf1(v[3]);
  o1.x = f2bf1(v[4]); o1.y = f2bf1(v[5]); o1.z = f2bf1(v[6]); o1.w = f2bf1(v[7]);
  *(us4*)dst = o0;
  *(us4*)(dst + 4) = o1;
}

// ---- unified MFMA flash attention, KVBLK=64 --------------------------------
__global__ __launch_bounds__(256) void attn_u64(
    const u16* __restrict__ qb, const u16* __restrict__ kg,
    const u16* __restrict__ vg, u16* __restrict__ aob_st) {
  const int i = blockIdx.x;  // 0..511
  const int pair = i & 255, half = i >> 8;
  const int bh = pair & 31;
  const int q8 = pair >> 5;
  const int qblk = half ? (15 - q8) : q8;
  const int b = bh >> 4, h = bh & 15;
  const int q0 = qblk * 64;
  const int tid = threadIdx.x, lane = tid & 63, w = tid >> 6;
  const int qw = q0 + w * 16;
  const int col = lane & 15, kpart = lane >> 4, rbase = kpart * 4;
  __shared__ u16 Ks[2][8192];
  __shared__ u16 Vs[2][8192];
  __shared__ u16 Pl[4][16 * 72];
  bf8 qf[4];
  {
    const u16* qp =
        qb + (size_t)(b * 1024 + qw + col) * 2048 + h * 128 + kpart * 8;
#pragma unroll
    for (int dc = 0; dc < 4; ++dc) qf[dc] = *(const bf8*)(qp + dc * 32);
  }
  f4 o[8];
#pragma unroll
  for (int df = 0; df < 8; ++df) o[df] = f4{0.f, 0.f, 0.f, 0.f};
  float m_r[4] = {-1e30f, -1e30f, -1e30f, -1e30f};
  float l_p[4] = {0.f, 0.f, 0.f, 0.f};
  const float scale = 0.08838834764831845f;
  const int nt_text = qblk + 1;
  const int nt = nt_text + 9;
  const u16* kbh = kg + (size_t)bh * (NKV * 128);
  const u16* vbh = vg + (size_t)bh * (NKV * 128);
  u16* pw = &Pl[w][0];

#define ASTG64(bi, kv0)                                                       \
  do {                                                                        \
    const u16* gk = kbh + (size_t)((kv0) >> 5) * 4096 + w * 2048 + lane * 8;  \
    GLDS(gk, &Ks[bi][w * 2048 + lane * 8]);                                   \
    GLDS(gk + 512, &Ks[bi][w * 2048 + 512 + lane * 8]);                       \
    GLDS(gk + 1024, &Ks[bi][w * 2048 + 1024 + lane * 8]);                     \
    GLDS(gk + 1536, &Ks[bi][w * 2048 + 1536 + lane * 8]);                     \
    const u16* gv = vbh + (size_t)((kv0) >> 3) * 1024 + w * 2048 + lane * 8;  \
    GLDS(gv, &Vs[bi][w * 2048 + lane * 8]);                                   \
    GLDS(gv + 512, &Vs[bi][w * 2048 + 512 + lane * 8]);                       \
    GLDS(gv + 1024, &Vs[bi][w * 2048 + 1024 + lane * 8]);                     \
    GLDS(gv + 1536, &Vs[bi][w * 2048 + 1536 + lane * 8]);                     \
  } while (0)

  ASTG64(0, 0);
  int cur = 0;
  for (int t = 0; t < nt; ++t) {
    const bool is_text = t < nt_text;
    const int kv0 = is_text ? (t << 6) : (1024 + ((t - nt_text) << 6));
    SB();
    if (t + 1 < nt) {
      const int t1 = t + 1;
      const int kv1 =
          (t1 < nt_text) ? (t1 << 6) : (1024 + ((t1 - nt_text) << 6));
      ASTG64(cur ^ 1, kv1);
      WVM(8);
    } else {
      WVM(0);
    }
    SB();
    const u16* ksb = &Ks[cur][0];
    const u16* vsb = &Vs[cur][0];
    f4 s0 = {0.f, 0.f, 0.f, 0.f}, s1 = {0.f, 0.f, 0.f, 0.f};
    f4 s2 = {0.f, 0.f, 0.f, 0.f}, s3 = {0.f, 0.f, 0.f, 0.f};
    __builtin_amdgcn_s_setprio(1);
#pragma unroll
    for (int dc = 0; dc < 4; ++dc) {
      const int dblk = dc * 4 + kpart;
      bf8 k0f = *(const bf8*)(ksb + (dblk * 32 + col) * 8);
      bf8 k1f = *(const bf8*)(ksb + (dblk * 32 + 16 + col) * 8);
      bf8 k2f = *(const bf8*)(ksb + 4096 + (dblk * 32 + col) * 8);
      bf8 k3f = *(const bf8*)(ksb + 4096 + (dblk * 32 + 16 + col) * 8);
      s0 = MFMA16(qf[dc], k0f, s0);
      s1 = MFMA16(qf[dc], k1f, s1);
      s2 = MFMA16(qf[dc], k2f, s2);
      s3 = MFMA16(qf[dc], k3f, s3);
    }
    __builtin_amdgcn_s_setprio(0);
    float sa[4][4], loc[4], p[4][4];
    bool grow = false;
    const bool need_mask = is_text && (kv0 + 63 > qw);
#pragma unroll
    for (int rr = 0; rr < 4; ++rr) {
      float a0 = s0[rr] * scale, a1 = s1[rr] * scale;
      float a2 = s2[rr] * scale, a3 = s3[rr] * scale;
      if (need_mask) {
        const int qg = qw + rbase + rr;
        if (kv0 + col > qg) a0 = -1e30f;
        if (kv0 + 16 + col > qg) a1 = -1e30f;
        if (kv0 + 32 + col > qg) a2 = -1e30f;
        if (kv0 + 48 + col > qg) a3 = -1e30f;
      }
      sa[rr][0] = a0; sa[rr][1] = a1; sa[rr][2] = a2; sa[rr][3] = a3;
      loc[rr] = fmaxf(fmaxf(a0, a1), fmaxf(a2, a3));
      grow |= (loc[rr] > m_r[rr] + 8.f);
    }
    if (__any(grow)) {
      float fr[4];
#pragma unroll
      for (int rr = 0; rr < 4; ++rr) {
        float mx = loc[rr];
        mx = fmaxf(mx, __shfl_xor(mx, 1));
        mx = fmaxf(mx, __shfl_xor(mx, 2));
        mx = fmaxf(mx, __shfl_xor(mx, 4));
        mx = fmaxf(mx, __shfl_xor(mx, 8));
        const float mn = fmaxf(m_r[rr], mx);
        fr[rr] = __expf(m_r[rr] - mn);
        m_r[rr] = mn;
#pragma unroll
        for (int jj = 0; jj < 4; ++jj) p[rr][jj] = __expf(sa[rr][jj] - mn);
        l_p[rr] = l_p[rr] * fr[rr] + p[rr][0] + p[rr][1] + p[rr][2] + p[rr][3];
      }
#pragma unroll
      for (int df = 0; df < 8; ++df) {
        o[df][0] *= fr[0]; o[df][1] *= fr[1];
        o[df][2] *= fr[2]; o[df][3] *= fr[3];
      }
    } else {
#pragma unroll
      for (int rr = 0; rr < 4; ++rr) {
#pragma unroll
        for (int jj = 0; jj < 4; ++jj) p[rr][jj] = __expf(sa[rr][jj] - m_r[rr]);
        l_p[rr] += p[rr][0] + p[rr][1] + p[rr][2] + p[rr][3];
      }
    }
#pragma unroll
    for (int rr = 0; rr < 4; ++rr) {
      pw[(rbase + rr) * 72 + col] = f2bf1(p[rr][0]);
      pw[(rbase + rr) * 72 + 16 + col] = f2bf1(p[rr][1]);
      pw[(rbase + rr) * 72 + 32 + col] = f2bf1(p[rr][2]);
      pw[(rbase + rr) * 72 + 48 + col] = f2bf1(p[rr][3]);
    }
    bf8 pa0 = *(const bf8*)(pw + col * 72 + kpart * 8);
    bf8 pa1 = *(const bf8*)(pw + col * 72 + 32 + kpart * 8);
    __builtin_amdgcn_s_setprio(1);
#pragma unroll
    for (int df = 0; df < 8; ++df) {
      bf8 vf0 = *(const bf8*)(vsb + (kpart * 128 + df * 16 + col) * 8);
      bf8 vf1 = *(const bf8*)(vsb + ((kpart + 4) * 128 + df * 16 + col) * 8);
      o[df] = MFMA16(pa0, vf0, o[df]);
      o[df] = MFMA16(pa1, vf1, o[df]);
    }
    __builtin_amdgcn_s_setprio(0);
    cur ^= 1;
  }
#undef ASTG64
  float inv[4];
#pragma unroll
  for (int rr = 0; rr < 4; ++rr) {
    float ps = l_p[rr];
    ps += __shfl_xor(ps, 1);
    ps += __shfl_xor(ps, 2);
    ps += __shfl_xor(ps, 4);
    ps += __shfl_xor(ps, 8);
    inv[rr] = 1.f / ps;
  }
#pragma unroll
  for (int rr = 0; rr < 4; ++rr) {
    const int m = b * 1024 + qw + rbase + rr;
    const int mb = m >> 6, fr3 = (m >> 4) & 3, r16 = m & 15;
#pragma unroll
    for (int df = 0; df < 8; ++df) {
      const int ncol = h * 128 + df * 16 + col;
      const int kb = ncol >> 6, kc = (ncol >> 5) & 1, ks3 = (ncol >> 3) & 3,
                j0 = ncol & 7;
      aob_st[((size_t)(mb * 32 + kb)) * 4096 +
             (((fr3 * 2 + kc) * 4 + ks3) * 16 + r16) * 8 + j0] =
          f2bf1(o[df][rr] * inv[rr]);
    }
  }
}

// ---------------------------------------------------------------------------
extern "C" void kernel_launch(void* const* d_in, const int* in_sizes, int n_in,
                              void* d_out, int out_size, void* d_ws,
                              size_t ws_size, hipStream_t stream) {
  const float* hs = (const float*)d_in[0];
  const float* img = (const float*)d_in[1];
  const float* wq = (const float*)d_in[2];
  const float* wk = (const float*)d_in[3];
  const float* wv = (const float*)d_in[4];
  const float* wo = (const float*)d_in[5];
  const float* cdw = (const float*)d_in[6];
  const float* ln1w = (const float*)d_in[7];
  const float* ln1b = (const float*)d_in[8];
  const float* plrw = (const float*)d_in[9];
  const float* piw = (const float*)d_in[10];
  const float* pib = (const float*)d_in[11];
  const float* ln2w = (const float*)d_in[12];
  const float* ln2b = (const float*)d_in[13];
  const float* offw = (const float*)d_in[14];
  const float* khw = (const float*)d_in[15];
  const float* khb = (const float*)d_in[16];
  const float* vhw = (const float*)d_in[17];
  const float* vhb = (const float*)d_in[18];
  float* outp = (float*)d_out;

  u16* wsp = (u16*)d_ws;
  const size_t SZ = 4194304;  // 2048*2048
  u16* hs_st = wsp;
  u16* wq_st = wsp + SZ;       // reused as aob_st after gemm
  u16* wk_st = wsp + 2 * SZ;
  u16* wv_st = wsp + 3 * SZ;
  u16* wo_st = wsp + 4 * SZ;   // live until gemm_out3
  u16* khw_st = wsp + 5 * SZ;
  u16* vhw_st = wsp + 6 * SZ;
  u16* qb_bf = wsp + 7 * SZ;
  u16* samp_st = wsp + 8 * SZ;       // 1152*2048 staged
  u16* kg = wsp + 8 * SZ + 2359296;  // 2*16*1600*128
  u16* vg = kg + 6553600;
  // fp32 scratch overlays kg/vg (dead before gemms)
  float* x1b = (float*)kg + 2359296;
  float* x2b = x1b + 2359296;
  float* poolb = x2b + 294912;
  float* gb = poolb + 4096;
  float* wtb = (float*)(vg + 6553600);  // 32768 floats, persistent
  u32* qctr = (u32*)(wtb + 32768);      // work-queue counter
  u16* aob_st = wq_st;

  dim3 blk(256);
  // L1a: dwconv3x3+silu+pool (256 blocks, 36.9 KB LDS)
  dwpool16<<<dim3(256), blk, 0, stream>>>(hs, cdw, x1b, poolb);
  // L1b: conversions (staged) + plrw^T (8.7 KB LDS -> 8 blocks/CU)
  f2bf_k8v<<<dim3(1024, 8), blk, 0, stream>>>(hs, wq, wk, wv, wo, khw, vhw,
                                              plrw, hs_st, wq_st, wk_st,
                                              wv_st, wo_st, khw_st, vhw_st,
                                              wtb);
  // L2: LN(512) + 1x1 conv + gate
  lnproj_gate<<<dim3(74), blk, 0, stream>>>(x1b, ln1w, ln1b, wtb, poolb, piw,
                                            pib, x2b, gb);
  // L3: LN(64)+offsets+tanh + bilinear sample -> staged samp
  pos_sample<<<dim3(B * K), blk, 0, stream>>>(x2b, gb, ln2w, ln2b, offw, img,
                                              samp_st);
  // L4: persistent work-queue GEMM (192 QKV + 288 fine HD tiles, 256 blocks)
  hipMemsetAsync(qctr, 0, 4, stream);
  gemm_queue<<<dim3(256), dim3(512), 0, stream>>>(
      hs_st, wq_st, wk_st, wv_st, samp_st, khw_st, vhw_st, khb, vhb, qb_bf,
      kg, vg, qctr);
  // L5: unified attention, KVBLK=64 (writes staged aob)
  attn_u64<<<dim3(512), blk, 0, stream>>>(qb_bf, kg, vg, aob_st);
  // L6: output projection (256 blocks, 3-deep pipeline)
  gemm_out3<<<dim3(256), blk, 0, stream>>>(aob_st, wo_st, outp);
}